// Round 13
// baseline (2167.736 us; speedup 1.0000x reference)
//
#include <hip/hip_runtime.h>
#include <hip/hip_bf16.h>

typedef __hip_bfloat16 bf16;
typedef unsigned short ush;
typedef short s16x8 __attribute__((ext_vector_type(8)));
typedef ush u16x4 __attribute__((ext_vector_type(4)));
typedef float f32x4 __attribute__((ext_vector_type(4)));

#define DEV __device__ __forceinline__

DEV float rcp_f(float x) { return __builtin_amdgcn_rcpf(x); }
DEV float sigmoid_f(float x) { return rcp_f(1.f + __expf(-x)); }
DEV float tanh_f(float x) { return 1.f - 2.f * rcp_f(__expf(2.f * x) + 1.f); }

DEV float u2f(ush u) { unsigned int v = ((unsigned int)u) << 16; float f; __builtin_memcpy(&f, &v, 4); return f; }
DEV ush f2u(float f) { bf16 h = __float2bfloat16(f); ush u; __builtin_memcpy(&u, &h, 2); return u; }

DEV f32x4 MFMA(s16x8 a, s16x8 b, f32x4 c) {
  return __builtin_amdgcn_mfma_f32_16x16x32_bf16(a, b, c, 0, 0, 0);
}

DEV s16x8 z8() {
  s16x8 v;
  for (int z = 0; z < 8; ++z) v[z] = 0;
  return v;
}

DEV f32x4 zf4() { f32x4 v; v[0] = v[1] = v[2] = v[3] = 0.f; return v; }

// swizzled element index within a [rows][32] bf16 chunk: 16B blocks XOR'd by (row>>1)&3
DEV int swz_idx(int row, int kk) { return row * 32 + (((kk >> 3) ^ ((row >> 1) & 3)) << 3) + (kk & 7); }
DEV int swz_blk(int row, int blk) { return row * 32 + ((blk ^ ((row >> 1) & 3)) << 3); }

// ---------------------------------------------------------------------------
// N=4096 graphs, K=8 nodes, n_in=14, H=128, k=3 iters. Inputs fp32.
// ROUND 13: per-graph MEGA-KERNEL. Block = 1 graph. eh/PqT/xh live entirely
// in LDS; only hsum/esum leave the block. 3 launches total.
// Weight layouts (prep_all):
//  WPQ  [5ck][768][32]: pq B (P half gates r,z,n1 from M_Wih[:, :142-mapped];
//                       Q half from M_Wih[:,142:284]); K pads: 14,15 & 144-159=0
//  WTh  [4ck][384][32]: edge h-phase A (M_Whh gates r,z,n)
//  WTu  [9ck][512][32]: node B (x-phase gates r,z,n1 / h-phase r,z,n2)
//  WBen1[128][32], WBen2[4ck][128][32], WBee1[128][32], WBee2[4ck][128][32]
//  biasM[4][128] (r,z fold bih+bhh; n1=bih_n; n2=bhh_n), biasU same, bn2rep[128][8]
// ---------------------------------------------------------------------------

__global__ __launch_bounds__(256) void prep_all(
    const float* __restrict__ MWih, const float* __restrict__ MWhh,
    const float* __restrict__ UWih, const float* __restrict__ UWhh,
    const float* __restrict__ EnW1, const float* __restrict__ EnW2,
    const float* __restrict__ EeW1, const float* __restrict__ EeW2,
    const float* __restrict__ MBih, const float* __restrict__ MBhh,
    const float* __restrict__ UBih, const float* __restrict__ UBhh,
    const float* __restrict__ GWih, const float* __restrict__ GWhh,
    const float* __restrict__ GBih, const float* __restrict__ GBhh,
    ush* __restrict__ WPQ, ush* __restrict__ WTh, ush* __restrict__ WTu,
    ush* __restrict__ WBen1, ush* __restrict__ WBen2,
    ush* __restrict__ WBee1, ush* __restrict__ WBee2,
    float* __restrict__ biasM, float* __restrict__ biasU,
    float* __restrict__ WT_G, float* __restrict__ biasG, ush* __restrict__ bn2rep)
{
  const int b = blockIdx.x, t = threadIdx.x;
  if (b < 480) {                        // WPQ: 5*768*32
    const int idx = b * 256 + t;
    const int ck = idx / 24576, rem = idx % 24576, n = rem >> 5, kk = rem & 31;
    const int k = ck * 32 + kk;
    const int half = (n >= 384);
    const int m = n - half * 384;
    const int g = m >> 7, c = m & 127;
    const int row = g * 128 + c;
    int col = -1;
    if (k < 14)                  col = k;
    else if (k >= 16 && k < 144) col = k - 2;
    if (half && col >= 0)        col += 142;
    WPQ[idx] = f2u((col >= 0) ? MWih[row * 284 + col] : 0.f);
  } else if (b < 672) {                 // WTh: 4*384*32
    const int idx = (b - 480) * 256 + t;
    const int ck = idx / 12288, rem = idx % 12288, n = rem >> 5, kk = rem & 31;
    const int g = n >> 7, c = n & 127;
    WTh[idx] = f2u(MWhh[(g * 128 + c) * 128 + ck * 32 + kk]);
  } else if (b < 1248) {                // WTu: 9*512*32 linear
    const int idx = (b - 672) * 256 + t;
    const int ck = idx >> 14, n = (idx >> 5) & 511, kk = idx & 31;
    const int k = ck * 32 + kk, gate = n >> 7, c = n & 127;
    float w = 0.f;
    const int row = (gate == 0) ? c : (gate == 1) ? 128 + c : 256 + c;
    if (k < 160) {
      int col = -1;
      if (k < 16)        { if (k < 14) col = k; }
      else if (k < 144)  col = 14 + (k - 16);
      if (gate != 3 && col >= 0) w = UWih[row * 142 + col];
    } else {
      if (gate != 2) w = UWhh[row * 128 + (k - 160)];
    }
    WTu[idx] = f2u(w);
  } else if (b < 1264) {                // WBen1: 128x32
    const int idx = (b - 1248) * 256 + t;
    const int n = (idx >> 5) & 127, kk = idx & 31;
    WBen1[idx] = f2u(kk < 14 ? EnW1[n * 14 + kk] : 0.f);
  } else if (b < 1328) {                // WBen2: 4*128*32
    const int idx = (b - 1264) * 256 + t;
    const int ck = idx >> 12, n = (idx >> 5) & 127, kk = idx & 31;
    WBen2[idx] = f2u(EnW2[n * 128 + ck * 32 + kk]);
  } else if (b < 1344) {                // WBee1: 128x32 pair
    const int idx = (b - 1328) * 256 + t;
    const int n = (idx >> 5) & 127, kk = idx & 31;
    int col = (kk < 16) ? (kk < 14 ? kk : -1) : (kk < 30 ? 14 + (kk - 16) : -1);
    WBee1[idx] = f2u(col >= 0 ? EeW1[n * 28 + col] : 0.f);
  } else if (b < 1408) {                // WBee2: 4*128*32
    const int idx = (b - 1344) * 256 + t;
    const int ck = idx >> 12, n = (idx >> 5) & 127, kk = idx & 31;
    WBee2[idx] = f2u(EeW2[n * 128 + ck * 32 + kk]);
  } else if (b < 1410) {                // biasM
    const int idx = (b - 1408) * 256 + t;
    const int g = idx >> 7, c = idx & 127;
    float v;
    if (g == 0)      v = MBih[c] + MBhh[c];
    else if (g == 1) v = MBih[128 + c] + MBhh[128 + c];
    else if (g == 2) v = MBih[256 + c];
    else             v = MBhh[256 + c];
    biasM[idx] = v;
  } else if (b < 1412) {                // biasU
    const int idx = (b - 1410) * 256 + t;
    const int g = idx >> 7, c = idx & 127;
    float v;
    if (g == 0)      v = UBih[c] + UBhh[c];
    else if (g == 1) v = UBih[128 + c] + UBhh[128 + c];
    else if (g == 2) v = UBih[256 + c];
    else             v = UBhh[256 + c];
    biasU[idx] = v;
  } else if (b < 2180) {                // WT_G interleaved fp32: 384*512
    const int idx = (b - 1412) * 256 + t;
    const int kc = idx >> 9, cg = (idx >> 2) & 127, gate = idx & 3;
    const int row = (gate == 0) ? cg : (gate == 1) ? cg + 128 : cg + 256;
    float v = 0.f;
    if (kc < 256) { if (gate != 3) v = GWih[row * 256 + kc]; }
    else          { if (gate != 2) v = GWhh[row * 128 + (kc - 256)]; }
    WT_G[idx] = v;
  } else if (b < 2182) {                // biasG
    const int idx = (b - 2180) * 256 + t;
    const int cg = idx >> 2, gate = idx & 3;
    float v;
    if (gate == 0)      v = GBih[cg] + GBhh[cg];
    else if (gate == 1) v = GBih[cg + 128] + GBhh[cg + 128];
    else if (gate == 2) v = GBih[cg + 256];
    else                v = GBhh[cg + 256];
    biasG[idx] = v;
  } else {                              // bn2rep: [128][8]
    const int idx = (b - 2182) * 256 + t;
    if (idx < 1024) bn2rep[idx] = f2u(MBhh[256 + (idx >> 3)]);
  }
}

// ---------------------------------------------------------------------------
// MEGA: block = 1 graph. LDS map (ush):
//  EH  [0,8192)      e_h 64x128, 4 swizzled chunks (also Ee Z1 before e_h^0)
//  PQL [8192,14336)  PqT-local: [(half*384+gate*128+c)][8 nodes]
//  XT  [14336,14464) towers 8x16 (row*16+k)
//  XH  [14464,15488) h 8x128 (row*128+c)
//  WK  [15488,20096) work: En A1/Z1, Ee A1, pqA (5x512), nodeA (9x512)
// ---------------------------------------------------------------------------
__global__ __launch_bounds__(256, 2) void mega(
    const float* __restrict__ towers,
    const ush* __restrict__ WPQ, const ush* __restrict__ WTh,
    const ush* __restrict__ WTu,
    const ush* __restrict__ WBen1, const float* __restrict__ EnB1,
    const ush* __restrict__ WBen2, const float* __restrict__ EnB2,
    const ush* __restrict__ WBee1, const float* __restrict__ EeB1,
    const ush* __restrict__ WBee2, const float* __restrict__ EeB2,
    const float* __restrict__ biasM, const float* __restrict__ biasU,
    const ush* __restrict__ bn2rep,
    float* __restrict__ hsum, float* __restrict__ esum)
{
  __shared__ ush L[20096];
  ush* EH  = L;
  ush* PQL = L + 8192;
  ush* XT  = L + 14336;
  ush* XH  = L + 14464;
  ush* WK  = L + 15488;
  const int gid = blockIdx.x;
  const int t = threadIdx.x, lane = t & 63, w = t >> 6;
  const int quad = lane >> 4, l15 = lane & 15;

  // ---- P0: towers -> XT ----
  if (t < 128) {
    const int row = t >> 4, k = t & 15;
    XT[row * 16 + k] = f2u(k < 14 ? towers[(gid * 8 + row) * 14 + k] : 0.f);
  }
  __syncthreads();

  // ---- P1: En MLP (M=8 in 16-row tile) -> XH ----
  if (t < 64) {
    const int row = t >> 2, gb = t & 3;
    s16x8 v = z8();
    if (row < 8 && gb < 2) v = *(const s16x8*)&XT[row * 16 + gb * 8];
    *(s16x8*)&WK[swz_blk(row, gb)] = v;
  }
  __syncthreads();
  {
    const s16x8 af0 = *(const s16x8*)&WK[swz_blk(l15, quad)];
    f32x4 e1[2] = {zf4(), zf4()};
    #pragma unroll
    for (int ct = 0; ct < 2; ++ct) {
      const int n = w * 32 + ct * 16 + l15;
      const s16x8 bf = *(const s16x8*)&WBen1[n * 32 + quad * 8];
      e1[ct] = MFMA(af0, bf, e1[ct]);
    }
    __syncthreads();                   // WK[0,512) dead
    #pragma unroll
    for (int ct = 0; ct < 2; ++ct) {
      const int col = w * 32 + ct * 16 + l15;
      const int ck2 = col >> 5, kk = col & 31;
      #pragma unroll
      for (int q = 0; q < 4; ++q) {
        const int row = quad * 4 + q;
        const float val = (row < 8) ? tanh_f(e1[ct][q] + EnB1[col]) : 0.f;
        WK[512 + ck2 * 512 + swz_idx(row, kk)] = f2u(val);
      }
    }
    __syncthreads();
    f32x4 e2[2] = {zf4(), zf4()};
    for (int ck2 = 0; ck2 < 4; ++ck2) {
      const s16x8 af = *(const s16x8*)&WK[512 + ck2 * 512 + swz_blk(l15, quad)];
      #pragma unroll
      for (int ct = 0; ct < 2; ++ct) {
        const int n = w * 32 + ct * 16 + l15;
        const s16x8 bf = *(const s16x8*)&WBen2[(ck2 * 128 + n) * 32 + quad * 8];
        e2[ct] = MFMA(af, bf, e2[ct]);
      }
    }
    if (quad < 2) {
      #pragma unroll
      for (int ct = 0; ct < 2; ++ct) {
        const int col = w * 32 + ct * 16 + l15;
        #pragma unroll
        for (int q = 0; q < 4; ++q)
          XH[(quad * 4 + q) * 128 + col] = f2u(tanh_f(e2[ct][q] + EnB2[col]));
      }
    }
  }
  __syncthreads();

  // ---- P2: Ee MLP (64 edge rows) -> e_h^0 in EH ----
  {
    const int gm = t >> 2, gb = t & 3;
    const int i = gm >> 3, j = gm & 7;
    const s16x8 v = (gb < 2) ? *(const s16x8*)&XT[i * 16 + gb * 8]
                             : *(const s16x8*)&XT[j * 16 + (gb - 2) * 8];
    *(s16x8*)&WK[swz_blk(gm, gb)] = v;
  }
  __syncthreads();
  {
    s16x8 af[4];
    #pragma unroll
    for (int rt = 0; rt < 4; ++rt)
      af[rt] = *(const s16x8*)&WK[swz_blk(rt * 16 + l15, quad)];
    f32x4 a1[4][2];
    #pragma unroll
    for (int rt = 0; rt < 4; ++rt) { a1[rt][0] = zf4(); a1[rt][1] = zf4(); }
    #pragma unroll
    for (int ct = 0; ct < 2; ++ct) {
      const int n = w * 32 + ct * 16 + l15;
      const s16x8 bf = *(const s16x8*)&WBee1[n * 32 + quad * 8];
      #pragma unroll
      for (int rt = 0; rt < 4; ++rt) a1[rt][ct] = MFMA(af[rt], bf, a1[rt][ct]);
    }
    // Z1 -> EH region
    #pragma unroll
    for (int ct = 0; ct < 2; ++ct) {
      const int col = w * 32 + ct * 16 + l15;
      const int ck2 = col >> 5, kk = col & 31;
      #pragma unroll
      for (int rt = 0; rt < 4; ++rt) {
        #pragma unroll
        for (int q = 0; q < 4; ++q) {
          const int m = rt * 16 + quad * 4 + q;
          EH[ck2 * 2048 + swz_idx(m, kk)] = f2u(tanh_f(a1[rt][ct][q] + EeB1[col]));
        }
      }
    }
    __syncthreads();
    f32x4 a2[4][2];
    #pragma unroll
    for (int rt = 0; rt < 4; ++rt) { a2[rt][0] = zf4(); a2[rt][1] = zf4(); }
    for (int ck2 = 0; ck2 < 4; ++ck2) {
      #pragma unroll
      for (int rt = 0; rt < 4; ++rt)
        af[rt] = *(const s16x8*)&EH[ck2 * 2048 + swz_blk(rt * 16 + l15, quad)];
      #pragma unroll
      for (int ct = 0; ct < 2; ++ct) {
        const int n = w * 32 + ct * 16 + l15;
        const s16x8 bf = *(const s16x8*)&WBee2[(ck2 * 128 + n) * 32 + quad * 8];
        #pragma unroll
        for (int rt = 0; rt < 4; ++rt) a2[rt][ct] = MFMA(af[rt], bf, a2[rt][ct]);
      }
    }
    __syncthreads();                   // all Z1 reads done -> overwrite EH
    #pragma unroll
    for (int ct = 0; ct < 2; ++ct) {
      const int col = w * 32 + ct * 16 + l15;
      #pragma unroll
      for (int rt = 0; rt < 4; ++rt) {
        #pragma unroll
        for (int q = 0; q < 4; ++q) {
          const int r = rt * 16 + quad * 4 + q;
          EH[(col >> 5) * 2048 + swz_idx(r, col & 31)] =
              f2u(tanh_f(a2[rt][ct][q] + EeB2[col]));
        }
      }
    }
  }
  __syncthreads();

  // ---- P3: k = 3 iterations, all in LDS ----
  for (int it = 0; it < 3; ++it) {
    // -- pq: PQL = [xh] @ [Wa|Wb]^T (+biasM fold on P half) --
    for (int idx = t; idx < 320; idx += 256) {
      const int ck = idx >> 6, r = (idx >> 2) & 15, gb = idx & 3;
      const int k0 = ck * 32 + gb * 8;
      s16x8 v = z8();
      if (r < 8) {
        if (k0 < 16)        v = *(const s16x8*)&XT[r * 16 + k0];
        else if (k0 < 144)  v = *(const s16x8*)&XH[r * 128 + (k0 - 16)];
      }
      *(s16x8*)&WK[ck * 512 + swz_blk(r, gb)] = v;
    }
    __syncthreads();
    #pragma unroll
    for (int half = 0; half < 2; ++half) {
      f32x4 pa[6];
      #pragma unroll
      for (int tl = 0; tl < 6; ++tl) pa[tl] = zf4();
      for (int ck = 0; ck < 5; ++ck) {
        const s16x8 af = *(const s16x8*)&WK[ck * 512 + swz_blk(l15, quad)];
        #pragma unroll
        for (int tl = 0; tl < 6; ++tl) {
          const int n = w * 96 + tl * 16 + l15;
          const s16x8 bf = *(const s16x8*)&WPQ[(ck * 768 + half * 384 + n) * 32 + quad * 8];
          pa[tl] = MFMA(af, bf, pa[tl]);
        }
      }
      if (quad < 2) {
        #pragma unroll
        for (int tl = 0; tl < 6; ++tl) {
          const int col = w * 96 + tl * 16 + l15;
          const float bv = half ? 0.f : biasM[col];
          u16x4 wv;
          #pragma unroll
          for (int q = 0; q < 4; ++q) wv[q] = f2u(pa[tl][q] + bv);
          *(u16x4*)&PQL[(half * 384 + col) * 8 + quad * 4] = wv;
        }
      }
    }
    __syncthreads();

    // -- edge GRU (2 sequential mt passes to cap VGPRs) --
    u16x4 ov[2][4];
    #pragma unroll
    for (int mt = 0; mt < 2; ++mt) {
      f32x4 aR4[4], aZ4[4], aN14[4], aN24[4];
      #pragma unroll
      for (int nt = 0; nt < 4; ++nt) { aR4[nt] = zf4(); aZ4[nt] = zf4(); aN14[nt] = zf4(); aN24[nt] = zf4(); }
      const int nb = w * 32 + mt * 16 + l15;
      const int ko = quad * 8;
      #pragma unroll
      for (int ck = 0; ck < 4; ++ck) {
        s16x8 be[4];
        #pragma unroll
        for (int nt = 0; nt < 4; ++nt)
          be[nt] = *(const s16x8*)&EH[ck * 2048 + swz_blk(nt * 16 + l15, quad)];
        const s16x8 aR = *(const s16x8*)&WTh[(ck * 384 + nb) * 32 + ko];
        const s16x8 aZ = *(const s16x8*)&WTh[(ck * 384 + 128 + nb) * 32 + ko];
        const s16x8 aN = *(const s16x8*)&WTh[(ck * 384 + 256 + nb) * 32 + ko];
        #pragma unroll
        for (int nt = 0; nt < 4; ++nt) {
          aR4[nt]  = MFMA(aR, be[nt], aR4[nt]);
          aZ4[nt]  = MFMA(aZ, be[nt], aZ4[nt]);
          aN24[nt] = MFMA(aN, be[nt], aN24[nt]);
        }
      }
      // indicator chunk
      {
        const int c = w * 32 + mt * 16 + l15;
        s16x8 iR = z8(), iZ = z8(), iN1 = z8(), iN2 = z8();
        if (quad == 0) {
          iR  = *(const s16x8*)&PQL[(c) * 8];
          iZ  = *(const s16x8*)&PQL[(128 + c) * 8];
          iN1 = *(const s16x8*)&PQL[(256 + c) * 8];
          iN2 = *(const s16x8*)&bn2rep[c * 8];
        } else if (quad == 1) {
          iR  = *(const s16x8*)&PQL[(384 + c) * 8];
          iZ  = *(const s16x8*)&PQL[(512 + c) * 8];
          iN1 = *(const s16x8*)&PQL[(640 + c) * 8];
        }
        #pragma unroll
        for (int nt = 0; nt < 4; ++nt) {
          const int erow = nt * 16 + l15;
          s16x8 bI = z8();
          if (quad == 0)      bI[erow >> 3] = (short)0x3F80;
          else if (quad == 1) bI[erow & 7]  = (short)0x3F80;
          aR4[nt]  = MFMA(iR,  bI, aR4[nt]);
          aZ4[nt]  = MFMA(iZ,  bI, aZ4[nt]);
          aN14[nt] = MFMA(iN1, bI, aN14[nt]);
          aN24[nt] = MFMA(iN2, bI, aN24[nt]);
        }
      }
      // epilogue compute (reads hp from EH, no writes yet)
      const int hc0 = w * 32 + mt * 16 + quad * 4;
      const int ck2 = hc0 >> 5, kkB = hc0 & 31;
      #pragma unroll
      for (int nt = 0; nt < 4; ++nt) {
        const int erow = nt * 16 + l15;
        const u16x4 hp4 = *(const u16x4*)&EH[ck2 * 2048 + swz_blk(erow, kkB >> 3) + (kkB & 7)];
        #pragma unroll
        for (int q = 0; q < 4; ++q) {
          const float rg = sigmoid_f(aR4[nt][q]);
          const float zg = sigmoid_f(aZ4[nt][q]);
          const float nn = tanh_f(aN14[nt][q] + rg * aN24[nt][q]);
          const float hp = u2f(hp4[q]);
          ov[mt][nt][q] = f2u(nn + zg * (hp - nn));
        }
      }
    }
    __syncthreads();                   // all EH reads done
    #pragma unroll
    for (int mt = 0; mt < 2; ++mt) {
      const int hc0 = w * 32 + mt * 16 + quad * 4;
      const int ck2 = hc0 >> 5, kkB = hc0 & 31;
      #pragma unroll
      for (int nt = 0; nt < 4; ++nt) {
        const int erow = nt * 16 + l15;
        *(u16x4*)&EH[ck2 * 2048 + swz_blk(erow, kkB >> 3) + (kkB & 7)] = ov[mt][nt];
      }
    }
    __syncthreads();

    // -- node GRU: A = [towers|edges|pad|h] (M=8 in 16-row tile) --
    for (int idx = t; idx < 576; idx += 256) {
      const int ck = idx >> 6, r = (idx >> 2) & 15, gb = idx & 3;
      const int k0 = ck * 32 + gb * 8;
      s16x8 v = z8();
      if (r < 8) {
        if (k0 < 16) {
          v = *(const s16x8*)&XT[r * 16 + k0];
        } else if (k0 < 144) {
          if (r < 7) {
            const int c0 = k0 - 16;
            v = *(const s16x8*)&EH[(c0 >> 5) * 2048 + swz_blk(r * 8 + r + 1, (c0 >> 3) & 3)];
          }
        } else if (k0 >= 160) {
          v = *(const s16x8*)&XH[r * 128 + (k0 - 160)];
        }
      }
      *(s16x8*)&WK[ck * 512 + swz_blk(r, gb)] = v;
    }
    __syncthreads();
    #pragma unroll
    for (int s = 0; s < 2; ++s) {
      f32x4 nR = zf4(), nZ = zf4(), nN1 = zf4(), nN2 = zf4();
      const int nb = w * 32 + s * 16 + l15;
      for (int ck = 0; ck < 9; ++ck) {
        const s16x8 af = *(const s16x8*)&WK[ck * 512 + swz_blk(l15, quad)];
        const s16x8 bR = *(const s16x8*)&WTu[(ck * 512 + nb) * 32 + quad * 8];
        const s16x8 bZ = *(const s16x8*)&WTu[(ck * 512 + 128 + nb) * 32 + quad * 8];
        nR = MFMA(af, bR, nR);
        nZ = MFMA(af, bZ, nZ);
        if (ck < 5) {
          const s16x8 bN = *(const s16x8*)&WTu[(ck * 512 + 256 + nb) * 32 + quad * 8];
          nN1 = MFMA(af, bN, nN1);
        } else {
          const s16x8 bN = *(const s16x8*)&WTu[(ck * 512 + 384 + nb) * 32 + quad * 8];
          nN2 = MFMA(af, bN, nN2);
        }
      }
      if (quad < 2) {
        const int hcol = w * 32 + s * 16 + l15;
        const float bR = biasU[hcol], bZ = biasU[128 + hcol];
        const float bN1 = biasU[256 + hcol], bN2 = biasU[384 + hcol];
        #pragma unroll
        for (int q = 0; q < 4; ++q) {
          const int r = quad * 4 + q;
          const float hp = u2f(XH[r * 128 + hcol]);
          const float rg = sigmoid_f(nR[q] + bR);
          const float zg = sigmoid_f(nZ[q] + bZ);
          const float nn = tanh_f(nN1[q] + bN1 + rg * (nN2[q] + bN2));
          XH[r * 128 + hcol] = f2u(nn + zg * (hp - nn));
        }
      }
    }
    __syncthreads();
  }

  // ---- P4: per-graph sums ----
  if (t < 128) {
    float hs = 0.f, es = 0.f;
    #pragma unroll
    for (int i = 0; i < 8; ++i) hs += u2f(XH[i * 128 + t]);
    #pragma unroll
    for (int i = 0; i < 7; ++i) {
      const int erow = i * 8 + i + 1;
      es += u2f(EH[(t >> 5) * 2048 + swz_idx(erow, t & 31)]);
    }
    hsum[gid * 128 + t] = hs;
    esum[gid * 128 + t] = es;
  }
}

// ---------------------------------------------------------------------------
// global GRU (h_prev = 0) fused with output head: 16 graphs per block.
// ---------------------------------------------------------------------------
__global__ __launch_bounds__(256) void gru_global_out(
    const float* __restrict__ hsum, const float* __restrict__ esum,
    const float* __restrict__ WT, const float* __restrict__ bias,
    const float* __restrict__ OW, const float* __restrict__ Ob,
    float* __restrict__ out)
{
  constexpr int KT = 384;
  __shared__ float4 ATl4[KT * 4];
  __shared__ float4 Bl4[16 * 128];
  __shared__ float gmat[16 * 128];
  __shared__ float red[16 * 4];
  float* ATl = (float*)ATl4;
  const int t = threadIdx.x;
  const int rowBase = blockIdx.x * 16;
  for (int idx = t; idx < KT * 16; idx += 256) {
    const int kc = idx >> 4, r = idx & 15, grow = rowBase + r;
    float v = 0.f;
    if (kc < 128)      v = hsum[grow * 128 + kc];
    else if (kc < 256) v = esum[grow * 128 + (kc - 128)];
    ATl[idx] = v;
  }
  const int c = t & 127, rh = t >> 7;
  float accR[8], accZ[8], accN1[8];
  #pragma unroll
  for (int rr = 0; rr < 8; ++rr) { accR[rr] = 0.f; accZ[rr] = 0.f; accN1[rr] = 0.f; }
  const float4* WT4 = (const float4*)WT;
  for (int ck = 0; ck < 16; ++ck) {
    __syncthreads();
    #pragma unroll
    for (int ii = 0; ii < 8; ++ii) { const int idx = t + ii * 256; Bl4[idx] = WT4[ck * 2048 + idx]; }
    __syncthreads();
    const int kb = ck * 16;
    #pragma unroll
    for (int kcl = 0; kcl < 16; ++kcl) {
      const float4 wv = Bl4[kcl * 128 + c];
      const float4 a0 = ATl4[(kb + kcl) * 4 + rh * 2];
      const float4 a1 = ATl4[(kb + kcl) * 4 + rh * 2 + 1];
      const float av[8] = {a0.x, a0.y, a0.z, a0.w, a1.x, a1.y, a1.z, a1.w};
      #pragma unroll
      for (int rr = 0; rr < 8; ++rr) {
        accR[rr]  += wv.x * av[rr];
        accZ[rr]  += wv.y * av[rr];
        accN1[rr] += wv.z * av[rr];
      }
    }
  }
  const float4 bb = ((const float4*)bias)[c];
  const float ow = OW[c];
  #pragma unroll
  for (int rr = 0; rr < 8; ++rr) {
    const float rg = sigmoid_f(accR[rr] + bb.x);
    const float zg = sigmoid_f(accZ[rr] + bb.y);
    const float nn = tanh_f(accN1[rr] + bb.z + rg * bb.w);
    gmat[(rh * 8 + rr) * 128 + c] = (1.f - zg) * nn * ow;
  }
  __syncthreads();
  if (t < 64) {
    const int r = t >> 2, part = t & 3;
    float s = 0.f;
    #pragma unroll
    for (int cc = 0; cc < 32; ++cc) s += gmat[r * 128 + part * 32 + cc];
    red[r * 4 + part] = s;
  }
  __syncthreads();
  if (t < 16) {
    const float s = red[t * 4] + red[t * 4 + 1] + red[t * 4 + 2] + red[t * 4 + 3];
    out[rowBase + t] = sigmoid_f(s + Ob[0]);
  }
}

// ---------------------------------------------------------------------------
extern "C" void kernel_launch(void* const* d_in, const int* in_sizes, int n_in,
                              void* d_out, int out_size, void* d_ws, size_t ws_size,
                              hipStream_t stream)
{
  (void)in_sizes; (void)n_in; (void)out_size; (void)ws_size;
  const float* towers = (const float*)d_in[0];
  const float* EnW1 = (const float*)d_in[1];
  const float* EnB1 = (const float*)d_in[2];
  const float* EnW2 = (const float*)d_in[3];
  const float* EnB2 = (const float*)d_in[4];
  const float* EeW1 = (const float*)d_in[5];
  const float* EeB1 = (const float*)d_in[6];
  const float* EeW2 = (const float*)d_in[7];
  const float* EeB2 = (const float*)d_in[8];
  const float* UWih = (const float*)d_in[9];
  const float* UWhh = (const float*)d_in[10];
  const float* UBih = (const float*)d_in[11];
  const float* UBhh = (const float*)d_in[12];
  const float* MWih = (const float*)d_in[13];
  const float* MWhh = (const float*)d_in[14];
  const float* MBih = (const float*)d_in[15];
  const float* MBhh = (const float*)d_in[16];
  const float* GWih = (const float*)d_in[17];
  const float* GWhh = (const float*)d_in[18];
  const float* GBih = (const float*)d_in[19];
  const float* GBhh = (const float*)d_in[20];
  const float* OW   = (const float*)d_in[21];
  const float* Ob   = (const float*)d_in[22];

  char* ws = (char*)d_ws;
  size_t off = 0;
  auto take = [&](size_t b) { void* p = ws + off; off = (off + b + 255) & ~(size_t)255; return p; };
  float* hsum   = (float*)take((size_t)4096 * 128 * 4);
  float* esum   = (float*)take((size_t)4096 * 128 * 4);
  ush*   WPQ    = (ush*)take((size_t)5 * 768 * 32 * 2);
  ush*   WTh    = (ush*)take((size_t)4 * 384 * 32 * 2);
  ush*   WTu    = (ush*)take((size_t)9 * 512 * 32 * 2);
  ush*   WBen1  = (ush*)take((size_t)128 * 32 * 2);
  ush*   WBen2  = (ush*)take((size_t)4 * 128 * 32 * 2);
  ush*   WBee1  = (ush*)take((size_t)128 * 32 * 2);
  ush*   WBee2  = (ush*)take((size_t)4 * 128 * 32 * 2);
  float* biasM  = (float*)take(512 * 4);
  float* biasU  = (float*)take(512 * 4);
  float* WT_G   = (float*)take((size_t)384 * 512 * 4);
  float* biasG  = (float*)take(512 * 4);
  ush*   bn2rep = (ush*)take(128 * 8 * 2);

  prep_all<<<2186, 256, 0, stream>>>(
      MWih, MWhh, UWih, UWhh, EnW1, EnW2, EeW1, EeW2,
      MBih, MBhh, UBih, UBhh, GWih, GWhh, GBih, GBhh,
      WPQ, WTh, WTu, WBen1, WBen2, WBee1, WBee2,
      biasM, biasU, WT_G, biasG, bn2rep);

  mega<<<4096, 256, 0, stream>>>(
      towers, WPQ, WTh, WTu,
      WBen1, EnB1, WBen2, EnB2, WBee1, EeB1, WBee2, EeB2,
      biasM, biasU, bn2rep, hsum, esum);

  gru_global_out<<<256, 256, 0, stream>>>(hsum, esum, WT_G, biasG, OW, Ob, (float*)d_out);
}

// Round 14
// 448.629 us; speedup vs baseline: 4.8319x; 4.8319x over previous
//
#include <hip/hip_runtime.h>
#include <hip/hip_bf16.h>

typedef __hip_bfloat16 bf16;
typedef unsigned short ush;
typedef short s16x8 __attribute__((ext_vector_type(8)));
typedef ush u16x4 __attribute__((ext_vector_type(4)));
typedef float f32x4 __attribute__((ext_vector_type(4)));

#define DEV __device__ __forceinline__

DEV float rcp_f(float x) { return __builtin_amdgcn_rcpf(x); }
DEV float sigmoid_f(float x) { return rcp_f(1.f + __expf(-x)); }
DEV float tanh_f(float x) { return 1.f - 2.f * rcp_f(__expf(2.f * x) + 1.f); }

DEV float u2f(ush u) { unsigned int v = ((unsigned int)u) << 16; float f; __builtin_memcpy(&f, &v, 4); return f; }
DEV ush f2u(float f) { bf16 h = __float2bfloat16(f); ush u; __builtin_memcpy(&u, &h, 2); return u; }

DEV f32x4 MFMA(s16x8 a, s16x8 b, f32x4 c) {
  return __builtin_amdgcn_mfma_f32_16x16x32_bf16(a, b, c, 0, 0, 0);
}

DEV s16x8 z8() {
  s16x8 v;
  for (int z = 0; z < 8; ++z) v[z] = 0;
  return v;
}

// swizzled element index within a [rows][32] bf16 chunk: 16B blocks XOR'd by (row>>1)&3
DEV int swz_idx(int row, int kk) { return row * 32 + (((kk >> 3) ^ ((row >> 1) & 3)) << 3) + (kk & 7); }
DEV int swz_blk(int row, int blk) { return row * 32 + ((blk ^ ((row >> 1) & 3)) << 3); }

// ---------------------------------------------------------------------------
// N=4096 graphs, K=8 nodes, n_in=14, H=128, k=3 iters. Inputs fp32.
// xh:  [32768][144] bf16 = [towers(14), pad(2), h(128)]
// eh:  [262144][128] bf16 (e_h^0 never hits HBM)
// PqT: [4096][768][8] bf16, produced fused in enc_en_pq / gru_node_pq.
// ROUND 14 = round-9 structure (best measured) + sums folded into LAST edge
// (esum) and last node (hsum); sums2 kernel deleted.
// ---------------------------------------------------------------------------

__global__ __launch_bounds__(256) void prep_all(
    const float* __restrict__ towers,
    const float* __restrict__ MWih, const float* __restrict__ MWhh,
    const float* __restrict__ UWih, const float* __restrict__ UWhh,
    const float* __restrict__ EnW1, const float* __restrict__ EnW2,
    const float* __restrict__ EeW1, const float* __restrict__ EeW2,
    const float* __restrict__ MBih, const float* __restrict__ MBhh,
    const float* __restrict__ UBih, const float* __restrict__ UBhh,
    const float* __restrict__ GWih, const float* __restrict__ GWhh,
    const float* __restrict__ GBih, const float* __restrict__ GBhh,
    ush* __restrict__ xh, ush* __restrict__ WPQ, ush* __restrict__ WTh,
    ush* __restrict__ WTu, ush* __restrict__ WBen1, ush* __restrict__ WBen2,
    ush* __restrict__ WBee1, ush* __restrict__ WBee2,
    float* __restrict__ biasM, float* __restrict__ biasU,
    float* __restrict__ WT_G, float* __restrict__ biasG, ush* __restrict__ bn2rep)
{
  const int b = blockIdx.x, t = threadIdx.x;
  if (b < 2048) {                       // xh towers part: 32768*16
    const int idx = b * 256 + t;
    const int row = idx >> 4, kk = idx & 15;
    xh[row * 144 + kk] = f2u(kk < 14 ? towers[row * 14 + kk] : 0.f);
  } else if (b < 2528) {                // WPQ: 5*768*32 linear fragment layout
    const int idx = (b - 2048) * 256 + t;
    const int ck = idx / 24576, rem = idx % 24576, n = rem >> 5, kk = rem & 31;
    const int k = ck * 32 + kk;
    const int half = (n >= 384);
    const int m = n - half * 384;
    const int g = m >> 7, c = m & 127;
    const int row = g * 128 + c;
    int col = -1;
    if (k < 14)                  col = k;
    else if (k >= 16 && k < 144) col = k - 2;
    if (half && col >= 0)        col += 142;
    WPQ[idx] = f2u((col >= 0) ? MWih[row * 284 + col] : 0.f);
  } else if (b < 2720) {                // WTh: 4*384*32 linear
    const int idx = (b - 2528) * 256 + t;
    const int ck = idx / 12288, rem = idx % 12288, n = rem >> 5, kk = rem & 31;
    const int g = n >> 7, c = n & 127;
    WTh[idx] = f2u(MWhh[(g * 128 + c) * 128 + ck * 32 + kk]);
  } else if (b < 3296) {                // WTu: 9*512*32 SWIZZLED (LDS-staged B)
    const int idx = (b - 2720) * 256 + t;
    const int ck = idx >> 14, n = (idx >> 5) & 511, kk = idx & 31;
    const int k = ck * 32 + kk, gate = n >> 7, c = n & 127;
    float w = 0.f;
    const int row = (gate == 0) ? c : (gate == 1) ? 128 + c : 256 + c;
    if (k < 160) {
      int col = -1;
      if (k < 16)        { if (k < 14) col = k; }
      else if (k < 144)  col = 14 + (k - 16);
      if (gate != 3 && col >= 0) w = UWih[row * 142 + col];
    } else {
      if (gate != 2) w = UWhh[row * 128 + (k - 160)];
    }
    WTu[ck * 16384 + swz_idx(n, kk)] = f2u(w);
  } else if (b < 3312) {                // WBen1: 128x32 linear
    const int idx = (b - 3296) * 256 + t;
    const int n = (idx >> 5) & 127, kk = idx & 31;
    WBen1[idx] = f2u(kk < 14 ? EnW1[n * 14 + kk] : 0.f);
  } else if (b < 3376) {                // WBen2: 4*128*32 linear
    const int idx = (b - 3312) * 256 + t;
    const int ck = idx >> 12, n = (idx >> 5) & 127, kk = idx & 31;
    WBen2[idx] = f2u(EnW2[n * 128 + ck * 32 + kk]);
  } else if (b < 3392) {                // WBee1: 128x32 pair linear
    const int idx = (b - 3376) * 256 + t;
    const int n = (idx >> 5) & 127, kk = idx & 31;
    int col = (kk < 16) ? (kk < 14 ? kk : -1) : (kk < 30 ? 14 + (kk - 16) : -1);
    WBee1[idx] = f2u(col >= 0 ? EeW1[n * 28 + col] : 0.f);
  } else if (b < 3456) {                // WBee2: 4*128*32 linear
    const int idx = (b - 3392) * 256 + t;
    const int ck = idx >> 12, n = (idx >> 5) & 127, kk = idx & 31;
    WBee2[idx] = f2u(EeW2[n * 128 + ck * 32 + kk]);
  } else if (b < 3458) {                // biasM [4 gates][128]
    const int idx = (b - 3456) * 256 + t;
    const int g = idx >> 7, c = idx & 127;
    float v;
    if (g == 0)      v = MBih[c] + MBhh[c];
    else if (g == 1) v = MBih[128 + c] + MBhh[128 + c];
    else if (g == 2) v = MBih[256 + c];
    else             v = MBhh[256 + c];
    biasM[idx] = v;
  } else if (b < 3460) {                // biasU
    const int idx = (b - 3458) * 256 + t;
    const int g = idx >> 7, c = idx & 127;
    float v;
    if (g == 0)      v = UBih[c] + UBhh[c];
    else if (g == 1) v = UBih[128 + c] + UBhh[128 + c];
    else if (g == 2) v = UBih[256 + c];
    else             v = UBhh[256 + c];
    biasU[idx] = v;
  } else if (b < 4228) {                // WT_G interleaved fp32: 384*512
    const int idx = (b - 3460) * 256 + t;
    const int kc = idx >> 9, cg = (idx >> 2) & 127, gate = idx & 3;
    const int row = (gate == 0) ? cg : (gate == 1) ? cg + 128 : cg + 256;
    float v = 0.f;
    if (kc < 256) { if (gate != 3) v = GWih[row * 256 + kc]; }
    else          { if (gate != 2) v = GWhh[row * 128 + (kc - 256)]; }
    WT_G[idx] = v;
  } else if (b < 4230) {                // biasG
    const int idx = (b - 4228) * 256 + t;
    const int cg = idx >> 2, gate = idx & 3;
    float v;
    if (gate == 0)      v = GBih[cg] + GBhh[cg];
    else if (gate == 1) v = GBih[cg + 128] + GBhh[cg + 128];
    else if (gate == 2) v = GBih[cg + 256];
    else                v = GBhh[cg + 256];
    biasG[idx] = v;
  } else {                              // bn2rep: [128][8] = bhh_n replicated
    const int idx = (b - 4230) * 256 + t;   // 1024
    bn2rep[idx] = f2u(MBhh[256 + (idx >> 3)]);
  }
}

// ---------------------------------------------------------------------------
// Shared pq phase: rows 64 (As5 = 5 chunks x [64][32] swizzled), cols 768 via
// 2 sequential halves, B direct-global WPQ.
// ---------------------------------------------------------------------------
DEV void pq_phase(ush* As5, const ush* __restrict__ WPQ,
                  const float* __restrict__ biasM, ush* __restrict__ PqT,
                  int rowBase, int lane, int w)
{
  const int quad = lane >> 4, l15 = lane & 15;
  for (int half = 0; half < 2; ++half) {
    f32x4 acc[6][4];
    #pragma unroll
    for (int tl = 0; tl < 6; ++tl)
      #pragma unroll
      for (int rt = 0; rt < 4; ++rt) {
        #pragma unroll
        for (int q = 0; q < 4; ++q) acc[tl][rt][q] = 0.f;
      }
    for (int ck = 0; ck < 5; ++ck) {
      s16x8 af[4];
      #pragma unroll
      for (int rt = 0; rt < 4; ++rt)
        af[rt] = *(const s16x8*)&As5[ck * 2048 + swz_blk(rt * 16 + l15, quad)];
      #pragma unroll
      for (int tl = 0; tl < 6; ++tl) {
        const int n = w * 96 + tl * 16 + l15;
        const s16x8 bf = *(const s16x8*)&WPQ[(ck * 768 + half * 384 + n) * 32 + quad * 8];
        #pragma unroll
        for (int rt = 0; rt < 4; ++rt) acc[tl][rt] = MFMA(af[rt], bf, acc[tl][rt]);
      }
    }
    #pragma unroll
    for (int tl = 0; tl < 6; ++tl) {
      const int col = w * 96 + tl * 16 + l15;
      const float bv = half ? 0.f : biasM[col];
      #pragma unroll
      for (int rt = 0; rt < 4; ++rt) {
        const int row0 = rowBase + rt * 16 + quad * 4;
        const int g = row0 >> 3, n0 = row0 & 7;
        u16x4 wv;
        #pragma unroll
        for (int q = 0; q < 4; ++q) wv[q] = f2u(acc[tl][rt][q] + bv);
        *(u16x4*)&PqT[((size_t)g * 768 + half * 384 + col) * 8 + n0] = wv;
      }
    }
  }
}

DEV void pq_stage_towers(ush* As5, const ush* __restrict__ xh, int rowBase, int t)
{
  const int gm = t >> 2, gb = t & 3, grow = rowBase + gm;
  if (gb < 2) {
    const s16x8 v = *(const s16x8*)(xh + grow * 144 + gb * 8);
    *(s16x8*)&As5[swz_blk(gm, gb)] = v;
  } else {
    *(s16x8*)&As5[4 * 2048 + swz_blk(gm, gb)] = z8();
  }
}

// ---------------------------------------------------------------------------
// Node encoder (E_n MLP) fused with initial P/Q GEMM. 64 node-rows per block.
// ---------------------------------------------------------------------------
__global__ __launch_bounds__(256, 2) void enc_en_pq(
    ush* __restrict__ xh,
    const ush* __restrict__ WB1, const float* __restrict__ b1,
    const ush* __restrict__ WB2, const float* __restrict__ b2,
    const ush* __restrict__ WPQ, const float* __restrict__ biasM,
    ush* __restrict__ PqT)
{
  __shared__ ush smem[10240];          // A1 [0,1024) | Z1 [1024,9216) ; As5 aliases
  ush* A1  = smem;
  ush* Z1  = smem + 1024;
  ush* As5 = smem;
  const int t = threadIdx.x, lane = t & 63, w = t >> 6;
  const int rowBase = blockIdx.x * 64;
  const int quad = lane >> 4, l15 = lane & 15;

  {
    const int gm = t >> 2, gb = t & 3, grow = rowBase + gm;
    s16x8 v = z8();
    if (gb < 2) v = *(const s16x8*)(xh + grow * 144 + gb * 8);
    *(s16x8*)&A1[swz_blk(gm, gb)] = v;
  }
  __syncthreads();

  s16x8 af[4];
  #pragma unroll
  for (int rt = 0; rt < 4; ++rt)
    af[rt] = *(const s16x8*)&A1[swz_blk(rt * 16 + l15, quad)];
  f32x4 acc1[4][2];
  #pragma unroll
  for (int rt = 0; rt < 4; ++rt)
    #pragma unroll
    for (int ct = 0; ct < 2; ++ct) {
      #pragma unroll
      for (int q = 0; q < 4; ++q) acc1[rt][ct][q] = 0.f;
    }
  #pragma unroll
  for (int ct = 0; ct < 2; ++ct) {
    const int n = w * 32 + ct * 16 + l15;
    const s16x8 bf = *(const s16x8*)&WB1[n * 32 + quad * 8];
    #pragma unroll
    for (int rt = 0; rt < 4; ++rt) acc1[rt][ct] = MFMA(af[rt], bf, acc1[rt][ct]);
  }
  #pragma unroll
  for (int ct = 0; ct < 2; ++ct) {
    const int col = w * 32 + ct * 16 + l15;
    const int kk = col & 31;
    #pragma unroll
    for (int rt = 0; rt < 4; ++rt) {
      #pragma unroll
      for (int q = 0; q < 4; ++q) {
        const int m = rt * 16 + quad * 4 + q;
        Z1[w * 2048 + swz_idx(m, kk)] = f2u(tanh_f(acc1[rt][ct][q] + b1[col]));
      }
    }
  }
  __syncthreads();

  f32x4 acc2[4][2];
  #pragma unroll
  for (int rt = 0; rt < 4; ++rt)
    #pragma unroll
    for (int ct = 0; ct < 2; ++ct) {
      #pragma unroll
      for (int q = 0; q < 4; ++q) acc2[rt][ct][q] = 0.f;
    }
  for (int ck2 = 0; ck2 < 4; ++ck2) {
    #pragma unroll
    for (int rt = 0; rt < 4; ++rt)
      af[rt] = *(const s16x8*)&Z1[ck2 * 2048 + swz_blk(rt * 16 + l15, quad)];
    #pragma unroll
    for (int ct = 0; ct < 2; ++ct) {
      const int n = w * 32 + ct * 16 + l15;
      const s16x8 bf = *(const s16x8*)&WB2[(ck2 * 128 + n) * 32 + quad * 8];
      #pragma unroll
      for (int rt = 0; rt < 4; ++rt) acc2[rt][ct] = MFMA(af[rt], bf, acc2[rt][ct]);
    }
  }
  __syncthreads();                     // Z1/A1 dead -> As5 alias safe

  #pragma unroll
  for (int ct = 0; ct < 2; ++ct) {
    const int col = w * 32 + ct * 16 + l15;
    const int k = 16 + col, ck = k >> 5, kk = k & 31;
    #pragma unroll
    for (int rt = 0; rt < 4; ++rt) {
      #pragma unroll
      for (int q = 0; q < 4; ++q) {
        const int r = rt * 16 + quad * 4 + q;
        const ush hv = f2u(tanh_f(acc2[rt][ct][q] + b2[col]));
        xh[(rowBase + r) * 144 + 16 + col] = hv;
        As5[ck * 2048 + swz_idx(r, kk)] = hv;
      }
    }
  }
  pq_stage_towers(As5, xh, rowBase, t);
  __syncthreads();
  pq_phase(As5, WPQ, biasM, PqT, rowBase, lane, w);
}

// ---------------------------------------------------------------------------
// Edge GRU (transposed-C). eh tile staged in LDS (wave-shared, 4x reuse);
// WTh/PqT direct global (wave-partitioned). FIRST: inline Ee MLP (aliased).
// LAST: sparse eh store (rows j==i+1) + esum computed in-kernel.
// ---------------------------------------------------------------------------
template<int FIRST, int LAST>
__global__ __launch_bounds__(256, 2) void edge_mfma(
    ush* __restrict__ eh, const ush* __restrict__ WTh,
    const ush* __restrict__ PqT, const ush* __restrict__ bn2rep,
    const ush* __restrict__ xh,
    const ush* __restrict__ WB1, const float* __restrict__ b1,
    const ush* __restrict__ WB2, const float* __restrict__ b2,
    float* __restrict__ esum)
{
  __shared__ ush smem[FIRST ? 9216 : (LAST ? 9984 : 8192)];
  ush* As = smem;                      // e_h 64x128 swizzled [0,8192)
  float* esL = (float*)(smem + 8192);  // LAST: [7][128] fp32
  const int t = threadIdx.x, lane = t & 63, w = t >> 6;
  const int g = blockIdx.x, rowBase = g * 64;
  const int quad = lane >> 4, l15 = lane & 15;

  if (FIRST) {
    ush* A1 = smem;                    // [0,1024)
    ush* Z1 = smem + 1024;             // [1024,9216)
    {
      const int gm = t >> 2, gb = t & 3;
      const int i = gm >> 3, j = gm & 7;
      const s16x8 v = (gb < 2) ? *(const s16x8*)(xh + (g * 8 + i) * 144 + gb * 8)
                               : *(const s16x8*)(xh + (g * 8 + j) * 144 + (gb - 2) * 8);
      *(s16x8*)&A1[swz_blk(gm, gb)] = v;
    }
    __syncthreads();
    s16x8 af[4];
    #pragma unroll
    for (int rt = 0; rt < 4; ++rt)
      af[rt] = *(const s16x8*)&A1[swz_blk(rt * 16 + l15, quad)];
    f32x4 acc1[4][2];
    #pragma unroll
    for (int rt = 0; rt < 4; ++rt)
      #pragma unroll
      for (int ct = 0; ct < 2; ++ct) {
        #pragma unroll
        for (int q = 0; q < 4; ++q) acc1[rt][ct][q] = 0.f;
      }
    #pragma unroll
    for (int ct = 0; ct < 2; ++ct) {
      const int n = w * 32 + ct * 16 + l15;
      const s16x8 bf = *(const s16x8*)&WB1[n * 32 + quad * 8];
      #pragma unroll
      for (int rt = 0; rt < 4; ++rt) acc1[rt][ct] = MFMA(af[rt], bf, acc1[rt][ct]);
    }
    __syncthreads();                   // A1 reads done before Z1 writes overlap
    #pragma unroll
    for (int ct = 0; ct < 2; ++ct) {
      const int col = w * 32 + ct * 16 + l15;
      const int kk = col & 31;
      #pragma unroll
      for (int rt = 0; rt < 4; ++rt) {
        #pragma unroll
        for (int q = 0; q < 4; ++q) {
          const int m = rt * 16 + quad * 4 + q;
          Z1[w * 2048 + swz_idx(m, kk)] = f2u(tanh_f(acc1[rt][ct][q] + b1[col]));
        }
      }
    }
    __syncthreads();
    f32x4 acc2[4][2];
    #pragma unroll
    for (int rt = 0; rt < 4; ++rt)
      #pragma unroll
      for (int ct = 0; ct < 2; ++ct) {
        #pragma unroll
        for (int q = 0; q < 4; ++q) acc2[rt][ct][q] = 0.f;
      }
    for (int ck2 = 0; ck2 < 4; ++ck2) {
      #pragma unroll
      for (int rt = 0; rt < 4; ++rt)
        af[rt] = *(const s16x8*)&Z1[ck2 * 2048 + swz_blk(rt * 16 + l15, quad)];
      #pragma unroll
      for (int ct = 0; ct < 2; ++ct) {
        const int n = w * 32 + ct * 16 + l15;
        const s16x8 bf = *(const s16x8*)&WB2[(ck2 * 128 + n) * 32 + quad * 8];
        #pragma unroll
        for (int rt = 0; rt < 4; ++rt) acc2[rt][ct] = MFMA(af[rt], bf, acc2[rt][ct]);
      }
    }
    __syncthreads();                   // Z1 reads done -> As alias safe
    #pragma unroll
    for (int ct = 0; ct < 2; ++ct) {
      const int col = w * 32 + ct * 16 + l15;
      const int kk = col & 31;
      #pragma unroll
      for (int rt = 0; rt < 4; ++rt) {
        #pragma unroll
        for (int q = 0; q < 4; ++q) {
          const int r = rt * 16 + quad * 4 + q;
          As[(col >> 5) * 2048 + swz_idx(r, kk)] = f2u(tanh_f(acc2[rt][ct][q] + b2[col]));
        }
      }
    }
  } else {
    const int gm = t >> 2, gb = t & 3;
    #pragma unroll
    for (int ck = 0; ck < 4; ++ck) {
      const s16x8 v = *(const s16x8*)(eh + (size_t)(rowBase + gm) * 128 + ck * 32 + gb * 8);
      *(s16x8*)&As[ck * 2048 + swz_blk(gm, gb)] = v;
    }
  }
  __syncthreads();

  f32x4 accR[2][4], accZ[2][4], accN1[2][4], accN2[2][4];
  #pragma unroll
  for (int mt = 0; mt < 2; ++mt)
    #pragma unroll
    for (int nt = 0; nt < 4; ++nt) {
      #pragma unroll
      for (int q = 0; q < 4; ++q) { accR[mt][nt][q] = 0.f; accZ[mt][nt][q] = 0.f; accN1[mt][nt][q] = 0.f; accN2[mt][nt][q] = 0.f; }
    }

  // h-phase: D += WTh · eh^T  (gates r, z, n2); B from LDS, A direct-global
  #pragma unroll
  for (int ck = 0; ck < 4; ++ck) {
    s16x8 be[4];
    #pragma unroll
    for (int nt = 0; nt < 4; ++nt)
      be[nt] = *(const s16x8*)&As[ck * 2048 + swz_blk(nt * 16 + l15, quad)];
    #pragma unroll
    for (int mt = 0; mt < 2; ++mt) {
      const int nb = w * 32 + mt * 16 + l15;
      const int ko = quad * 8;
      const s16x8 aR = *(const s16x8*)&WTh[(ck * 384 + nb) * 32 + ko];
      const s16x8 aZ = *(const s16x8*)&WTh[(ck * 384 + 128 + nb) * 32 + ko];
      const s16x8 aN = *(const s16x8*)&WTh[(ck * 384 + 256 + nb) * 32 + ko];
      #pragma unroll
      for (int nt = 0; nt < 4; ++nt) {
        accR[mt][nt]  = MFMA(aR, be[nt], accR[mt][nt]);
        accZ[mt][nt]  = MFMA(aZ, be[nt], accZ[mt][nt]);
        accN2[mt][nt] = MFMA(aN, be[nt], accN2[mt][nt]);
      }
    }
  }

  // indicator chunk: A from PqT, B = in-register one-hot of (i, j)
  {
    s16x8 bI[4];
    #pragma unroll
    for (int nt = 0; nt < 4; ++nt) {
      const int erow = nt * 16 + l15;
      s16x8 v = z8();
      if (quad == 0)      v[erow >> 3] = (short)0x3F80;
      else if (quad == 1) v[erow & 7]  = (short)0x3F80;
      bI[nt] = v;
    }
    #pragma unroll
    for (int mt = 0; mt < 2; ++mt) {
      const int c = w * 32 + mt * 16 + l15;
      s16x8 aR = z8(), aZ = z8(), aN1 = z8(), aN2 = z8();
      if (quad == 0) {
        const ush* base = PqT + (size_t)g * 768 * 8;
        aR  = *(const s16x8*)&base[(c) * 8];
        aZ  = *(const s16x8*)&base[(128 + c) * 8];
        aN1 = *(const s16x8*)&base[(256 + c) * 8];
        aN2 = *(const s16x8*)&bn2rep[c * 8];
      } else if (quad == 1) {
        const ush* base = PqT + ((size_t)g * 768 + 384) * 8;
        aR  = *(const s16x8*)&base[(c) * 8];
        aZ  = *(const s16x8*)&base[(128 + c) * 8];
        aN1 = *(const s16x8*)&base[(256 + c) * 8];
      }
      #pragma unroll
      for (int nt = 0; nt < 4; ++nt) {
        accR[mt][nt]  = MFMA(aR,  bI[nt], accR[mt][nt]);
        accZ[mt][nt]  = MFMA(aZ,  bI[nt], accZ[mt][nt]);
        accN1[mt][nt] = MFMA(aN1, bI[nt], accN1[mt][nt]);
        accN2[mt][nt] = MFMA(aN2, bI[nt], accN2[mt][nt]);
      }
    }
  }

  // epilogue: h_prev from LDS As; LAST also stages esum rows into esL
  #pragma unroll
  for (int mt = 0; mt < 2; ++mt) {
    const int hc0 = w * 32 + mt * 16 + quad * 4;
    const int ck2 = hc0 >> 5, kkB = hc0 & 31;
    #pragma unroll
    for (int nt = 0; nt < 4; ++nt) {
      const int erow = nt * 16 + l15;
      if (LAST && (erow & 7) != (erow >> 3) + 1) continue;   // only j==i+1 consumed
      const u16x4 hp4 = *(const u16x4*)&As[ck2 * 2048 + swz_blk(erow, kkB >> 3) + (kkB & 7)];
      u16x4 ov;
      float4 es4;
      #pragma unroll
      for (int q = 0; q < 4; ++q) {
        const float rg = sigmoid_f(accR[mt][nt][q]);
        const float zg = sigmoid_f(accZ[mt][nt][q]);
        const float nn = tanh_f(accN1[mt][nt][q] + rg * accN2[mt][nt][q]);
        const float hp = u2f(hp4[q]);
        ov[q] = f2u(nn + zg * (hp - nn));
        if (LAST) ((float*)&es4)[q] = u2f(ov[q]);
      }
      *(u16x4*)&eh[(size_t)(rowBase + erow) * 128 + hc0] = ov;
      if (LAST) *(float4*)&esL[(erow >> 3) * 128 + hc0] = es4;
    }
  }
  if (LAST) {
    __syncthreads();
    if (t < 128) {
      float es = 0.f;
      #pragma unroll
      for (int i = 0; i < 7; ++i) es += esL[i * 128 + t];
      esum[g * 128 + t] = es;
    }
  }
}

// ---------------------------------------------------------------------------
// Node GRU fused with next-iteration P/Q GEMM (r9 form: Bs LDS-staged per
// chunk). PQ=0 (last iter) additionally computes hsum in-kernel.
// ---------------------------------------------------------------------------
template<int PQ>
__global__ __launch_bounds__(256, 2) void gru_node_pq(
    ush* __restrict__ xh, const ush* __restrict__ eh,
    const ush* __restrict__ WT, const float* __restrict__ bias,
    const ush* __restrict__ WPQ, const float* __restrict__ biasM,
    ush* __restrict__ PqT, float* __restrict__ hsum)
{
  constexpr int NCH = 9, XCH = 5;
  __shared__ ush smem[17408];          // As [0,1024) | Bs [1024,17408) ; As5/hL alias Bs
  ush* As  = smem;
  ush* Bs  = smem + 1024;
  ush* As5 = smem + 1024;
  ush* hL  = smem + 1024;              // PQ=0: [64][128] bf16 h values
  const int t = threadIdx.x, lane = t & 63, w = t >> 6;
  const int rowBase = blockIdx.x * 64;
  const int quad = lane >> 4, l15 = lane & 15;
  const int gm = t >> 2, gb = t & 3, grow = rowBase + gm;

  f32x4 accR[4][2], accZ[4][2], accN1[4][2], accN2[4][2];
  #pragma unroll
  for (int rt = 0; rt < 4; ++rt)
    #pragma unroll
    for (int s = 0; s < 2; ++s) {
      #pragma unroll
      for (int q = 0; q < 4; ++q) { accR[rt][s][q] = 0.f; accZ[rt][s][q] = 0.f; accN1[rt][s][q] = 0.f; accN2[rt][s][q] = 0.f; }
    }

  for (int ck = 0; ck < NCH; ++ck) {
    const ush* wsrc = WT + ck * 16384;
    #pragma unroll
    for (int ii = 0; ii < 8; ++ii) {
      const int o = (t + ii * 256) * 8;
      *(s16x8*)&Bs[o] = *(const s16x8*)&wsrc[o];
    }
    {
      const int k0 = ck * 32 + gb * 8;
      s16x8 v = z8();
      if (k0 < 16)       v = *(const s16x8*)(xh + grow * 144 + k0);
      else if (k0 < 144) {
        const int i = grow & 7;
        if (i < 7) v = *(const s16x8*)(eh + (size_t)(grow * 8 + i + 1) * 128 + (k0 - 16));
      } else if (k0 >= 160) {
        v = *(const s16x8*)(xh + grow * 144 + 16 + (k0 - 160));
      }
      *(s16x8*)&As[swz_blk(gm, gb)] = v;
    }
    __syncthreads();

    s16x8 af[4];
    #pragma unroll
    for (int rt = 0; rt < 4; ++rt)
      af[rt] = *(const s16x8*)&As[swz_blk(rt * 16 + l15, quad)];
    if (ck < XCH) {
      #pragma unroll
      for (int s = 0; s < 2; ++s) {
        const int nb = w * 32 + s * 16 + l15;
        const s16x8 bR = *(const s16x8*)&Bs[swz_blk(0 * 128 + nb, quad)];
        const s16x8 bZ = *(const s16x8*)&Bs[swz_blk(1 * 128 + nb, quad)];
        const s16x8 bN = *(const s16x8*)&Bs[swz_blk(2 * 128 + nb, quad)];
        #pragma unroll
        for (int rt = 0; rt < 4; ++rt) {
          accR[rt][s]  = MFMA(af[rt], bR, accR[rt][s]);
          accZ[rt][s]  = MFMA(af[rt], bZ, accZ[rt][s]);
          accN1[rt][s] = MFMA(af[rt], bN, accN1[rt][s]);
        }
      }
    } else {
      #pragma unroll
      for (int s = 0; s < 2; ++s) {
        const int nb = w * 32 + s * 16 + l15;
        const s16x8 bR = *(const s16x8*)&Bs[swz_blk(0 * 128 + nb, quad)];
        const s16x8 bZ = *(const s16x8*)&Bs[swz_blk(1 * 128 + nb, quad)];
        const s16x8 bN = *(const s16x8*)&Bs[swz_blk(3 * 128 + nb, quad)];
        #pragma unroll
        for (int rt = 0; rt < 4; ++rt) {
          accR[rt][s]  = MFMA(af[rt], bR, accR[rt][s]);
          accZ[rt][s]  = MFMA(af[rt], bZ, accZ[rt][s]);
          accN2[rt][s] = MFMA(af[rt], bN, accN2[rt][s]);
        }
      }
    }
    __syncthreads();
  }

  // epilogue: write h to xh; PQ -> scatter to As5; !PQ -> stage hL for hsum
  #pragma unroll
  for (int s = 0; s < 2; ++s) {
    const int hcol = w * 32 + s * 16 + l15;
    const float bR = bias[hcol], bZ = bias[128 + hcol], bN1 = bias[256 + hcol], bN2 = bias[384 + hcol];
    const int k = 16 + hcol, ckh = k >> 5, kkh = k & 31;
    #pragma unroll
    for (int rt = 0; rt < 4; ++rt) {
      #pragma unroll
      for (int q = 0; q < 4; ++q) {
        const int r = rt * 16 + quad * 4 + q;
        const int row = rowBase + r;
        const float hp = u2f(xh[row * 144 + 16 + hcol]);
        const float rg = sigmoid_f(accR[rt][s][q] + bR);
        const float zg = sigmoid_f(accZ[rt][s][q] + bZ);
        const float nn = tanh_f(accN1[rt][s][q] + bN1 + rg * (accN2[rt][s][q] + bN2));
        const ush hv = f2u(nn + zg * (hp - nn));
        xh[row * 144 + 16 + hcol] = hv;
        if (PQ) As5[ckh * 2048 + swz_idx(r, kkh)] = hv;
        else    hL[r * 128 + hcol] = hv;
      }
    }
  }
  if (PQ) {
    pq_stage_towers(As5, xh, rowBase, t);
    __syncthreads();
    pq_phase(As5, WPQ, biasM, PqT, rowBase, lane, w);
  } else {
    __syncthreads();
    for (int idx = t; idx < 1024; idx += 256) {
      const int g8 = idx >> 7, c = idx & 127;
      float hs = 0.f;
      #pragma unroll
      for (int i = 0; i < 8; ++i) hs += u2f(hL[(g8 * 8 + i) * 128 + c]);
      hsum[(blockIdx.x * 8 + g8) * 128 + c] = hs;
    }
  }
}

// ---------------------------------------------------------------------------
// global GRU (h_prev = 0) fused with output head: 16 graphs per block.
// ---------------------------------------------------------------------------
__global__ __launch_bounds__(256) void gru_global_out(
    const float* __restrict__ hsum, const float* __restrict__ esum,
    const float* __restrict__ WT, const float* __restrict__ bias,
    const float* __restrict__ OW, const float* __restrict__ Ob,
    float* __restrict__ out)
{
  constexpr int KT = 384;
  __shared__ float4 ATl4[KT * 4];
  __shared__ float4 Bl4[16 * 128];
  __shared__ float gmat[16 * 128];
  __shared__ float red[16 * 4];
  float* ATl = (float*)ATl4;
  const int t = threadIdx.x;
  const int rowBase = blockIdx.x * 16;
  for (int idx = t; idx < KT * 16; idx += 256) {
    const int kc = idx >> 4, r = idx & 15, grow = rowBase + r;
    float v = 0.f;
    if (kc < 128)      v = hsum[grow * 128 + kc];
    else if (kc < 256) v = esum[grow * 128 + (kc - 128)];
    ATl[idx] = v;
  }
  const int c = t & 127, rh = t >> 7;
  float accR[8], accZ[8], accN1[8];
  #pragma unroll
  for (int rr = 0; rr < 8; ++rr) { accR[rr] = 0.f; accZ[rr] = 0.f; accN1[rr] = 0.f; }
  const float4* WT4 = (const float4*)WT;
  for (int ck = 0; ck < 16; ++ck) {
    __syncthreads();
    #pragma unroll
    for (int ii = 0; ii < 8; ++ii) { const int idx = t + ii * 256; Bl4[idx] = WT4[ck * 2048 + idx]; }
    __syncthreads();
    const int kb = ck * 16;
    #pragma unroll
    for (int kcl = 0; kcl < 16; ++kcl) {
      const float4 wv = Bl4[kcl * 128 + c];
      const float4 a0 = ATl4[(kb + kcl) * 4 + rh * 2];
      const float4 a1 = ATl4[(kb + kcl) * 4 + rh * 2 + 1];
      const float av[8] = {a0.x, a0.y, a0.z, a0.w, a1.x, a1.y, a1.z, a1.w};
      #pragma unroll
      for (int rr = 0; rr < 8; ++rr) {
        accR[rr]  += wv.x * av[rr];
        accZ[rr]  += wv.y * av[rr];
        accN1[rr] += wv.z * av[rr];
      }
    }
  }
  const float4 bb = ((const float4*)bias)[c];
  const float ow = OW[c];
  #pragma unroll
  for (int rr = 0; rr < 8; ++rr) {
    const float rg = sigmoid_f(accR[rr] + bb.x);
    const float zg = sigmoid_f(accZ[rr] + bb.y);
    const float nn = tanh_f(accN1[rr] + bb.z + rg * bb.w);
    gmat[(rh * 8 + rr) * 128 + c] = (1.f - zg) * nn * ow;
  }
  __syncthreads();
  if (t < 64) {
    const int r = t >> 2, part = t & 3;
    float s = 0.f;
    #pragma unroll
    for (int cc = 0; cc < 32; ++cc) s += gmat[r * 128 + part * 32 + cc];
    red[r * 4 + part] = s;
  }
  __syncthreads();
  if (t < 16) {
    const float s = red[t * 4] + red[t * 4 + 1] + red[t * 4 + 2] + red[t * 4 + 3];
    out[rowBase + t] = sigmoid_f(s + Ob[0]);
  }
}

// ---------------------------------------------------------------------------
extern "C" void kernel_launch(void* const* d_in, const int* in_sizes, int n_in,
                              void* d_out, int out_size, void* d_ws, size_t ws_size,
                              hipStream_t stream)
{
  (void)in_sizes; (void)n_in; (void)out_size; (void)ws_size;
  const float* towers = (const float*)d_in[0];
  const float* EnW1 = (const float*)d_in[1];
  const float* EnB1 = (const float*)d_in[2];
  const float* EnW2 = (const float*)d_in[3];
  const float* EnB2 = (const float*)d_in[4];
  const float* EeW1 = (const float*)d_in[5];
  const float* EeB1 = (const float*)d_in[6];
  const float* EeW2 = (const float*)d_in[7];
  const float* EeB2 = (const float*)d_in[8];
  const float* UWih = (const float*)d_in[9];
  const float* UWhh = (const float*)d_in[10];
  const float* UBih = (const float*)d_in[11];
  const float* UBhh = (const float*)d_in[12];
  const float* MWih = (const float*)d_in[13];
  const float* MWhh = (const float*)d_in[14];
  const float* MBih = (const float*)d_in[15];
  const float* MBhh = (const float*)d_in[16];
  const float* GWih = (const float*)d_in[17];
  const float* GWhh = (const float*)d_in[18];
  const float* GBih = (const float*)d_in[19];
  const float* GBhh = (const float*)d_in[20];
  const float* OW   = (const float*)d_in[21];
  const float* Ob   = (const float*)d_in[22];

  char* ws = (char*)d_ws;
  size_t off = 0;
  auto take = [&](size_t b) { void* p = ws + off; off = (off + b + 255) & ~(size_t)255; return p; };
  ush*   xh     = (ush*)take((size_t)32768 * 144 * 2);
  ush*   eh     = (ush*)take((size_t)262144 * 128 * 2);
  ush*   PqT    = (ush*)take((size_t)4096 * 768 * 8 * 2);
  float* hsum   = (float*)take((size_t)4096 * 128 * 4);
  float* esum   = (float*)take((size_t)4096 * 128 * 4);
  ush*   WPQ    = (ush*)take((size_t)5 * 768 * 32 * 2);
  ush*   WTh    = (ush*)take((size_t)4 * 384 * 32 * 2);
  ush*   WTu    = (ush*)take((size_t)9 * 512 * 32 * 2);
  ush*   WBen1  = (ush*)take((size_t)128 * 32 * 2);
  ush*   WBen2  = (ush*)take((size_t)4 * 128 * 32 * 2);
  ush*   WBee1  = (ush*)take((size_t)128 * 32 * 2);
  ush*   WBee2  = (ush*)take((size_t)4 * 128 * 32 * 2);
  float* biasM  = (float*)take(512 * 4);
  float* biasU  = (float*)take(512 * 4);
  float* WT_G   = (float*)take((size_t)384 * 512 * 4);
  float* biasG  = (float*)take(512 * 4);
  ush*   bn2rep = (ush*)take(128 * 8 * 2);

  prep_all<<<4234, 256, 0, stream>>>(
      towers, MWih, MWhh, UWih, UWhh, EnW1, EnW2, EeW1, EeW2,
      MBih, MBhh, UBih, UBhh, GWih, GWhh, GBih, GBhh,
      xh, WPQ, WTh, WTu, WBen1, WBen2, WBee1, WBee2,
      biasM, biasU, WT_G, biasG, bn2rep);

  enc_en_pq<<<512, 256, 0, stream>>>(xh, WBen1, EnB1, WBen2, EnB2, WPQ, biasM, PqT);

  // it 0: edge computes e_h^0 inline (Ee MLP) then GRU
  edge_mfma<1, 0><<<4096, 256, 0, stream>>>(eh, WTh, PqT, bn2rep, xh, WBee1, EeB1, WBee2, EeB2, esum);
  gru_node_pq<1><<<512, 256, 0, stream>>>(xh, eh, WTu, biasU, WPQ, biasM, PqT, hsum);
  // it 1
  edge_mfma<0, 0><<<4096, 256, 0, stream>>>(eh, WTh, PqT, bn2rep, xh, WBee1, EeB1, WBee2, EeB2, esum);
  gru_node_pq<1><<<512, 256, 0, stream>>>(xh, eh, WTu, biasU, WPQ, biasM, PqT, hsum);
  // it 2: edge sparse-stores + computes esum; node skips P/Q, computes hsum
  edge_mfma<0, 1><<<4096, 256, 0, stream>>>(eh, WTh, PqT, bn2rep, xh, WBee1, EeB1, WBee2, EeB2, esum);
  gru_node_pq<0><<<512, 256, 0, stream>>>(xh, eh, WTu, biasU, WPQ, biasM, PqT, hsum);

  // readout
  gru_global_out<<<256, 256, 0, stream>>>(hsum, esum, WT_G, biasG, OW, Ob, (float*)d_out);
}